// Round 1
// baseline (8924.725 us; speedup 1.0000x reference)
//
#include <hip/hip_runtime.h>
#include <math.h>

#define T_STEPS 12
#define N_NODES 10000
#define D_IN 256
#define H_DIM 512
#define H3 (3 * H_DIM)
#define E_EDGES 160000
#define NUM_CONVS 2

// ---------------- GEMM: C = A @ op(B) (+bias), fp32, 128x128x16 tile ----------------
// BT=true:  B is (Nn, K) row-major, compute A @ B^T   (GRU weight GEMMs)
// BT=false: B is (K, Nn) row-major, compute A @ B     (conv GEMMs)
// Requires: K % 16 == 0, Nn % 128 == 0 (true for all call sites). M may be ragged.
#define BM 128
#define BN 128
#define BKT 16

template <bool BT, bool BIAS>
__global__ __launch_bounds__(256) void gemm_kernel(
    const float* __restrict__ A, const float* __restrict__ B,
    const float* __restrict__ bias, float* __restrict__ C,
    int M, int Nn, int K) {
  __shared__ float As[BKT][BM + 4];
  __shared__ float Bs[BKT][BN + 4];
  const int tid = threadIdx.x;
  const int bm = blockIdx.y * BM;
  const int bn = blockIdx.x * BN;
  const int tx = tid & 15;   // n direction
  const int ty = tid >> 4;   // m direction
  const int lr = tid >> 2;        // 0..63 (row within tile for A/B-T loads)
  const int lk = (tid & 3) * 4;   // 0,4,8,12 (k quad)

  float acc[8][8];
#pragma unroll
  for (int i = 0; i < 8; ++i)
#pragma unroll
    for (int j = 0; j < 8; ++j) acc[i][j] = 0.0f;

  for (int kt = 0; kt < K; kt += BKT) {
    // ---- stage A tile (transposed store: As[k][m]) ----
#pragma unroll
    for (int hh = 0; hh < 2; ++hh) {
      int r = lr + hh * 64;
      int grow = bm + r;
      float4 v = make_float4(0.f, 0.f, 0.f, 0.f);
      if (grow < M) v = *(const float4*)(A + (size_t)grow * K + kt + lk);
      As[lk + 0][r] = v.x;
      As[lk + 1][r] = v.y;
      As[lk + 2][r] = v.z;
      As[lk + 3][r] = v.w;
    }
    // ---- stage B tile ----
    if (BT) {
#pragma unroll
      for (int hh = 0; hh < 2; ++hh) {
        int r = lr + hh * 64;
        float4 v = *(const float4*)(B + (size_t)(bn + r) * K + kt + lk);
        Bs[lk + 0][r] = v.x;
        Bs[lk + 1][r] = v.y;
        Bs[lk + 2][r] = v.z;
        Bs[lk + 3][r] = v.w;
      }
    } else {
      const int kk = tid >> 4;        // 0..15
      const int n4 = (tid & 15) * 4;  // 0..60 step 4
#pragma unroll
      for (int hh = 0; hh < 2; ++hh) {
        float4 v = *(const float4*)(B + (size_t)(kt + kk) * Nn + bn + n4 + hh * 64);
        *(float4*)&Bs[kk][n4 + hh * 64] = v;
      }
    }
    __syncthreads();
    // ---- compute ----
#pragma unroll
    for (int k = 0; k < BKT; ++k) {
      float a[8], b[8];
      *(float4*)(a + 0) = *(const float4*)&As[k][ty * 8 + 0];
      *(float4*)(a + 4) = *(const float4*)&As[k][ty * 8 + 4];
      *(float4*)(b + 0) = *(const float4*)&Bs[k][tx * 8 + 0];
      *(float4*)(b + 4) = *(const float4*)&Bs[k][tx * 8 + 4];
#pragma unroll
      for (int i = 0; i < 8; ++i)
#pragma unroll
        for (int j = 0; j < 8; ++j) acc[i][j] = fmaf(a[i], b[j], acc[i][j]);
    }
    __syncthreads();
  }
  // ---- epilogue ----
#pragma unroll
  for (int i = 0; i < 8; ++i) {
    int row = bm + ty * 8 + i;
    if (row >= M) continue;
    float* cp = C + (size_t)row * Nn + bn + tx * 8;
#pragma unroll
    for (int j4 = 0; j4 < 8; j4 += 4) {
      float4 v;
      v.x = acc[i][j4 + 0];
      v.y = acc[i][j4 + 1];
      v.z = acc[i][j4 + 2];
      v.w = acc[i][j4 + 3];
      if (BIAS) {
        const float* bp = bias + bn + tx * 8 + j4;
        v.x += bp[0];
        v.y += bp[1];
        v.z += bp[2];
        v.w += bp[3];
      }
      *(float4*)(cp + j4) = v;
    }
  }
}

// ---------------- graph preprocessing ----------------
__global__ void deg_kernel(const int* __restrict__ col, const float* __restrict__ w,
                           float* __restrict__ deg, int* __restrict__ counts) {
  int e = blockIdx.x * blockDim.x + threadIdx.x;
  if (e >= E_EDGES) return;
  int c = col[e];
  atomicAdd(&deg[c], w[e]);
  atomicAdd(&counts[c], 1);
}

__global__ void dinv_kernel(float* __restrict__ deg_dinv, float* __restrict__ selfw) {
  int n = blockIdx.x * blockDim.x + threadIdx.x;
  if (n >= N_NODES) return;
  float d = deg_dinv[n] + 1.0f;
  float di = 1.0f / sqrtf(d);
  deg_dinv[n] = di;      // in-place: deg -> dinv
  selfw[n] = 1.0f / d;   // dinv^2
}

// single-block exclusive scan over counts[0..n) -> offsets[0..n], offsets[n]=total
__global__ __launch_bounds__(1024) void scan_kernel(const int* __restrict__ counts,
                                                    int* __restrict__ offsets, int n) {
  __shared__ int smem[1024];
  __shared__ int carry_s;
  if (threadIdx.x == 0) carry_s = 0;
  __syncthreads();
  for (int base = 0; base < n; base += 1024) {
    int i = base + threadIdx.x;
    int v = (i < n) ? counts[i] : 0;
    smem[threadIdx.x] = v;
    __syncthreads();
    for (int off = 1; off < 1024; off <<= 1) {
      int t = (threadIdx.x >= off) ? smem[threadIdx.x - off] : 0;
      __syncthreads();
      smem[threadIdx.x] += t;
      __syncthreads();
    }
    if (i < n) offsets[i] = carry_s + smem[threadIdx.x] - v;  // exclusive
    int total = smem[1023];
    __syncthreads();
    if (threadIdx.x == 0) carry_s += total;
    __syncthreads();
  }
  if (threadIdx.x == 0) offsets[n] = carry_s;
}

__global__ void scatter_kernel(const int* __restrict__ row, const int* __restrict__ col,
                               const float* __restrict__ w, const float* __restrict__ dinv,
                               const int* __restrict__ offsets, int* __restrict__ cursor,
                               int* __restrict__ csr_row, float* __restrict__ csr_norm) {
  int e = blockIdx.x * blockDim.x + threadIdx.x;
  if (e >= E_EDGES) return;
  int r = row[e], c = col[e];
  float nrm = dinv[r] * w[e] * dinv[c];
  int pos = offsets[c] + atomicAdd(&cursor[c], 1);
  csr_row[pos] = r;
  csr_norm[pos] = nrm;
}

// ---------------- GRU gate fusion: h = gru(gi, gh, h) ----------------
__global__ __launch_bounds__(256) void gru_gate_kernel(const float* __restrict__ gi,
                                                       const float* __restrict__ gh,
                                                       float* __restrict__ h) {
  int idx = blockIdx.x * blockDim.x + threadIdx.x;
  if (idx >= N_NODES * H_DIM) return;
  int n = idx / H_DIM;
  int j = idx - n * H_DIM;
  const float* gin = gi + (size_t)n * H3;
  const float* ghn = gh + (size_t)n * H3;
  float ir = gin[j], iz = gin[H_DIM + j], inn = gin[2 * H_DIM + j];
  float hr = ghn[j], hz = ghn[H_DIM + j], hn = ghn[2 * H_DIM + j];
  float r = 1.0f / (1.0f + expf(-(ir + hr)));
  float z = 1.0f / (1.0f + expf(-(iz + hz)));
  float nv = tanhf(inn + r * hn);
  float ho = h[idx];
  h[idx] = (1.0f - z) * nv + z * ho;
}

// ---------------- GCN aggregation: h = relu(agg + selfw*hW + b) ----------------
// one wave per (node, 64-channel chunk); H/64 = 8 chunks
__global__ __launch_bounds__(256) void agg_kernel(
    const float* __restrict__ hW, const int* __restrict__ csr_row,
    const float* __restrict__ csr_norm, const int* __restrict__ offsets,
    const float* __restrict__ selfw, const float* __restrict__ bias,
    float* __restrict__ hout) {
  int gw = (blockIdx.x * blockDim.x + threadIdx.x) >> 6;
  int lane = threadIdx.x & 63;
  int n = gw >> 3;
  int c = ((gw & 7) << 6) | lane;
  if (n >= N_NODES) return;
  int beg = offsets[n], end = offsets[n + 1];
  float acc = 0.0f;
  for (int j = beg; j < end; ++j) {
    int r = csr_row[j];
    float wv = csr_norm[j];
    acc = fmaf(wv, hW[(size_t)r * H_DIM + c], acc);
  }
  float v = acc + selfw[n] * hW[(size_t)n * H_DIM + c] + bias[c];
  hout[(size_t)n * H_DIM + c] = v > 0.0f ? v : 0.0f;
}

// ---------------- final linear: out[n] = h[n,:] . lin_W + lin_b ----------------
__global__ __launch_bounds__(256) void lin_kernel(const float* __restrict__ h,
                                                  const float* __restrict__ lw,
                                                  const float* __restrict__ lb,
                                                  float* __restrict__ out) {
  int gw = (blockIdx.x * blockDim.x + threadIdx.x) >> 6;
  int lane = threadIdx.x & 63;
  if (gw >= N_NODES) return;
  const float* hr = h + (size_t)gw * H_DIM;
  float s = 0.0f;
#pragma unroll
  for (int k = 0; k < H_DIM / 64; ++k) s = fmaf(hr[lane + 64 * k], lw[lane + 64 * k], s);
#pragma unroll
  for (int off = 32; off > 0; off >>= 1) s += __shfl_down(s, off, 64);
  if (lane == 0) out[gw] = s + lb[0];
}

// ---------------- launch ----------------
extern "C" void kernel_launch(void* const* d_in, const int* in_sizes, int n_in,
                              void* d_out, int out_size, void* d_ws, size_t ws_size,
                              hipStream_t stream) {
  const float* xs = (const float*)d_in[0];
  const int* ei = (const int*)d_in[1];
  const float* ew = (const float*)d_in[2];
  const float* W_ih = (const float*)d_in[3];
  const float* W_hh = (const float*)d_in[4];
  const float* b_ih = (const float*)d_in[5];
  const float* b_hh = (const float*)d_in[6];
  const float* conv_W = (const float*)d_in[7];
  const float* conv_b = (const float*)d_in[8];
  const float* lin_W = (const float*)d_in[9];
  const float* lin_b = (const float*)d_in[10];
  float* out = (float*)d_out;

  const int* row = ei;
  const int* col = ei + E_EDGES;

  char* ws = (char*)d_ws;
  size_t off = 0;
  auto alloc = [&](size_t bytes) -> void* {
    void* p = ws + off;
    off += (bytes + 255) & ~(size_t)255;
    return p;
  };
  float* h = (float*)alloc((size_t)N_NODES * H_DIM * 4);
  float* gi = (float*)alloc((size_t)N_NODES * H3 * 4);
  float* gh = (float*)alloc((size_t)N_NODES * H3 * 4);
  float* hW = (float*)alloc((size_t)N_NODES * H_DIM * 4);
  float* dinv = (float*)alloc(N_NODES * 4);
  float* selfw = (float*)alloc(N_NODES * 4);
  float* csr_norm = (float*)alloc(E_EDGES * 4);
  int* csr_row = (int*)alloc(E_EDGES * 4);
  int* offsets = (int*)alloc((N_NODES + 1) * 4);
  int* counts = (int*)alloc(N_NODES * 4);
  int* cursor = (int*)alloc(N_NODES * 4);

  hipMemsetAsync(h, 0, (size_t)N_NODES * H_DIM * 4, stream);
  hipMemsetAsync(dinv, 0, N_NODES * 4, stream);
  hipMemsetAsync(counts, 0, N_NODES * 4, stream);
  hipMemsetAsync(cursor, 0, N_NODES * 4, stream);

  deg_kernel<<<(E_EDGES + 255) / 256, 256, 0, stream>>>(col, ew, dinv, counts);
  dinv_kernel<<<(N_NODES + 255) / 256, 256, 0, stream>>>(dinv, selfw);
  scan_kernel<<<1, 1024, 0, stream>>>(counts, offsets, N_NODES);
  scatter_kernel<<<(E_EDGES + 255) / 256, 256, 0, stream>>>(row, col, ew, dinv, offsets,
                                                            cursor, csr_row, csr_norm);

  dim3 blk(256);
  dim3 g_gru(H3 / BN, (N_NODES + BM - 1) / BM);
  dim3 g_conv(H_DIM / BN, (N_NODES + BM - 1) / BM);

  for (int t = 0; t < T_STEPS; ++t) {
    const float* xt = xs + (size_t)t * N_NODES * D_IN;
    gemm_kernel<true, true><<<g_gru, blk, 0, stream>>>(xt, W_ih, b_ih, gi, N_NODES, H3, D_IN);
    gemm_kernel<true, true><<<g_gru, blk, 0, stream>>>(h, W_hh, b_hh, gh, N_NODES, H3, H_DIM);
    gru_gate_kernel<<<(N_NODES * H_DIM + 255) / 256, 256, 0, stream>>>(gi, gh, h);
    for (int l = 0; l < NUM_CONVS; ++l) {
      gemm_kernel<false, false><<<g_conv, blk, 0, stream>>>(
          h, conv_W + (size_t)l * H_DIM * H_DIM, nullptr, hW, N_NODES, H_DIM, H_DIM);
      agg_kernel<<<(N_NODES * 8 + 3) / 4, 256, 0, stream>>>(hW, csr_row, csr_norm, offsets,
                                                            selfw, conv_b + l * H_DIM, h);
    }
    lin_kernel<<<(N_NODES + 3) / 4, 256, 0, stream>>>(h, lin_W, lin_b, out + (size_t)t * N_NODES);
  }
}

// Round 2
// 5305.026 us; speedup vs baseline: 1.6823x; 1.6823x over previous
//
#include <hip/hip_runtime.h>
#include <math.h>

#define T_STEPS 12
#define N_NODES 10000
#define MP 10112  // 79*128, padded M
#define D_IN 256
#define H_DIM 512
#define H3 1536
#define E_EDGES 160000
#define NUM_CONVS 2

typedef __bf16 bf16x8 __attribute__((ext_vector_type(8)));
typedef float floatx4 __attribute__((ext_vector_type(4)));
typedef unsigned short u16;

__device__ __forceinline__ u16 f2bf(float f) {
  unsigned int u = __float_as_uint(f);
  u += 0x7FFFu + ((u >> 16) & 1u);  // round-nearest-even (no NaN inputs)
  return (u16)(u >> 16);
}
__device__ __forceinline__ float bf2f(u16 s) {
  return __uint_as_float(((unsigned int)s) << 16);
}

__device__ __forceinline__ void glds16(const void* g, void* l) {
  __builtin_amdgcn_global_load_lds(
      (const __attribute__((address_space(1))) unsigned int*)g,
      (__attribute__((address_space(3))) unsigned int*)l, 16, 0, 0);
}

// ---------------- bf16x3 MFMA GEMM: C = (Ahi+Alo) @ (Bhi+Blo)^T (+bias) ----
// A*: (rows x K) bf16, rows padded to 128-mult; B*: (Nn x K) bf16.
// Tile 128x128, BK=32, 4 waves of 64x64 (4x4 of 16x16x32 MFMA).
// LDS 16B-slot XOR swizzle: slot(r,c) = r*4 + (c ^ ((r>>1)&3)) -> bank-group-
// uniform frag reads AND contiguous lane order for global_load_lds.
template <bool BIAS>
__global__ __launch_bounds__(256) void gemm_bf16x3(
    const u16* __restrict__ Ahi, const u16* __restrict__ Alo,
    const u16* __restrict__ Bhi, const u16* __restrict__ Blo,
    const float* __restrict__ bias, float* __restrict__ C,
    int M, int Nn, int K) {
  __shared__ u16 lds[4][4096];  // Ahi, Alo, Bhi, Blo tiles (8KB each)
  const int tid = threadIdx.x;
  const int lane = tid & 63;
  const int wave = tid >> 6;
  const int rbase = blockIdx.y * 128;
  const int cbase = blockIdx.x * 128;

  // staging: 512 slots/tile, 2 per thread
  const int s1 = tid, s2 = tid + 256;
  const int r1 = s1 >> 2, c1 = (s1 & 3) ^ ((r1 >> 1) & 3);
  const int r2 = s2 >> 2, c2 = (s2 & 3) ^ ((r2 >> 1) & 3);
  const u16* pah1 = Ahi + (size_t)(rbase + r1) * K + c1 * 8;
  const u16* pah2 = Ahi + (size_t)(rbase + r2) * K + c2 * 8;
  const u16* pal1 = Alo + (size_t)(rbase + r1) * K + c1 * 8;
  const u16* pal2 = Alo + (size_t)(rbase + r2) * K + c2 * 8;
  const u16* pbh1 = Bhi + (size_t)(cbase + r1) * K + c1 * 8;
  const u16* pbh2 = Bhi + (size_t)(cbase + r2) * K + c2 * 8;
  const u16* pbl1 = Blo + (size_t)(cbase + r1) * K + c1 * 8;
  const u16* pbl2 = Blo + (size_t)(cbase + r2) * K + c2 * 8;
  const int l1 = (s1 >> 6) << 9;  // wave-uniform LDS short-offset
  const int l2 = (s2 >> 6) << 9;

  // fragment addressing
  const int wr = (wave >> 1) * 64;
  const int wc = (wave & 1) * 64;
  const int lrow = lane & 15;
  const int kq = lane >> 4;
  const int swz = kq ^ ((lrow >> 1) & 3);
  const int aoff = (wr + lrow) * 32 + swz * 8;
  const int boff = (wc + lrow) * 32 + swz * 8;

  floatx4 acc[4][4];
#pragma unroll
  for (int i = 0; i < 4; ++i)
#pragma unroll
    for (int j = 0; j < 4; ++j) acc[i][j] = (floatx4){0.f, 0.f, 0.f, 0.f};

  for (int kt = 0; kt < K; kt += 32) {
    glds16(pah1 + kt, &lds[0][l1]);
    glds16(pah2 + kt, &lds[0][l2]);
    glds16(pal1 + kt, &lds[1][l1]);
    glds16(pal2 + kt, &lds[1][l2]);
    glds16(pbh1 + kt, &lds[2][l1]);
    glds16(pbh2 + kt, &lds[2][l2]);
    glds16(pbl1 + kt, &lds[3][l1]);
    glds16(pbl2 + kt, &lds[3][l2]);
    __syncthreads();
    bf16x8 ah[4], bh[4], bl[4];
#pragma unroll
    for (int i = 0; i < 4; ++i) ah[i] = *(const bf16x8*)&lds[0][aoff + i * 512];
#pragma unroll
    for (int j = 0; j < 4; ++j) bh[j] = *(const bf16x8*)&lds[2][boff + j * 512];
#pragma unroll
    for (int i = 0; i < 4; ++i)
#pragma unroll
      for (int j = 0; j < 4; ++j)
        acc[i][j] = __builtin_amdgcn_mfma_f32_16x16x32_bf16(ah[i], bh[j], acc[i][j], 0, 0, 0);
#pragma unroll
    for (int j = 0; j < 4; ++j) bl[j] = *(const bf16x8*)&lds[3][boff + j * 512];
#pragma unroll
    for (int i = 0; i < 4; ++i)
#pragma unroll
      for (int j = 0; j < 4; ++j)
        acc[i][j] = __builtin_amdgcn_mfma_f32_16x16x32_bf16(ah[i], bl[j], acc[i][j], 0, 0, 0);
#pragma unroll
    for (int i = 0; i < 4; ++i) {
      bf16x8 al = *(const bf16x8*)&lds[1][aoff + i * 512];
#pragma unroll
      for (int j = 0; j < 4; ++j)
        acc[i][j] = __builtin_amdgcn_mfma_f32_16x16x32_bf16(al, bh[j], acc[i][j], 0, 0, 0);
    }
    __syncthreads();
  }
  // epilogue: C/D layout col=lane&15, row=(lane>>4)*4+reg
#pragma unroll
  for (int j = 0; j < 4; ++j) {
    int col = cbase + wc + j * 16 + lrow;
    float bv = BIAS ? bias[col] : 0.0f;
#pragma unroll
    for (int i = 0; i < 4; ++i) {
      int r0 = rbase + wr + i * 16 + kq * 4;
#pragma unroll
      for (int rr = 0; rr < 4; ++rr) {
        int r = r0 + rr;
        if (r < M) C[(size_t)r * Nn + col] = acc[i][j][rr] + bv;
      }
    }
  }
}

// ---------------- split kernels ----------------
__global__ void split_pair(const float* __restrict__ W, u16* __restrict__ hi,
                           u16* __restrict__ lo, int n) {
  int i = blockIdx.x * 256 + threadIdx.x;
  if (i >= n) return;
  float v = W[i];
  u16 h = f2bf(v);
  hi[i] = h;
  lo[i] = f2bf(v - bf2f(h));
}

// conv_W[l][k][j] -> transposed split [l][j][k]
__global__ void split_convw(const float* __restrict__ W, u16* __restrict__ hi,
                            u16* __restrict__ lo) {
  int o = blockIdx.x * 256 + threadIdx.x;
  if (o >= NUM_CONVS * H_DIM * H_DIM) return;
  int k = o & 511, j = (o >> 9) & 511, l = o >> 18;
  float v = W[(size_t)l * H_DIM * H_DIM + (size_t)k * H_DIM + j];
  u16 h = f2bf(v);
  hi[o] = h;
  lo[o] = f2bf(v - bf2f(h));
}

// xs (T,N,D) -> padded (T,MP,D) bf16 hi/lo
__global__ void split_xs(const float* __restrict__ xs, u16* __restrict__ hi,
                         u16* __restrict__ lo) {
  int i = blockIdx.x * 256 + threadIdx.x;
  if (i >= T_STEPS * N_NODES * D_IN) return;
  int t = i / (N_NODES * D_IN);
  int rem = i - t * (N_NODES * D_IN);
  size_t o = (size_t)t * MP * D_IN + rem;
  float v = xs[i];
  u16 h = f2bf(v);
  hi[o] = h;
  lo[o] = f2bf(v - bf2f(h));
}

// ---------------- graph preprocessing ----------------
__global__ void deg_kernel(const int* __restrict__ col, const float* __restrict__ w,
                           float* __restrict__ deg, int* __restrict__ counts) {
  int e = blockIdx.x * blockDim.x + threadIdx.x;
  if (e >= E_EDGES) return;
  int c = col[e];
  atomicAdd(&deg[c], w[e]);
  atomicAdd(&counts[c], 1);
}

__global__ void dinv_kernel(float* __restrict__ deg_dinv, float* __restrict__ selfw) {
  int n = blockIdx.x * blockDim.x + threadIdx.x;
  if (n >= N_NODES) return;
  float d = deg_dinv[n] + 1.0f;
  float di = 1.0f / sqrtf(d);
  deg_dinv[n] = di;
  selfw[n] = 1.0f / d;
}

__global__ __launch_bounds__(1024) void scan_kernel(const int* __restrict__ counts,
                                                    int* __restrict__ offsets, int n) {
  __shared__ int smem[1024];
  __shared__ int carry_s;
  if (threadIdx.x == 0) carry_s = 0;
  __syncthreads();
  for (int base = 0; base < n; base += 1024) {
    int i = base + threadIdx.x;
    int v = (i < n) ? counts[i] : 0;
    smem[threadIdx.x] = v;
    __syncthreads();
    for (int off = 1; off < 1024; off <<= 1) {
      int t = (threadIdx.x >= off) ? smem[threadIdx.x - off] : 0;
      __syncthreads();
      smem[threadIdx.x] += t;
      __syncthreads();
    }
    if (i < n) offsets[i] = carry_s + smem[threadIdx.x] - v;
    int total = smem[1023];
    __syncthreads();
    if (threadIdx.x == 0) carry_s += total;
    __syncthreads();
  }
  if (threadIdx.x == 0) offsets[n] = carry_s;
}

__global__ void scatter_kernel(const int* __restrict__ row, const int* __restrict__ col,
                               const float* __restrict__ w, const float* __restrict__ dinv,
                               const int* __restrict__ offsets, int* __restrict__ cursor,
                               int* __restrict__ csr_row, float* __restrict__ csr_norm) {
  int e = blockIdx.x * blockDim.x + threadIdx.x;
  if (e >= E_EDGES) return;
  int r = row[e], c = col[e];
  float nrm = dinv[r] * w[e] * dinv[c];
  int pos = offsets[c] + atomicAdd(&cursor[c], 1);
  csr_row[pos] = r;
  csr_norm[pos] = nrm;
}

// ---------------- GRU gates + bf16 split of new h ----------------
__global__ __launch_bounds__(256) void gru_gate_split(
    const float* __restrict__ gi, const float* __restrict__ gh,
    const float* __restrict__ h, u16* __restrict__ Shi, u16* __restrict__ Slo) {
  int idx = blockIdx.x * 256 + threadIdx.x;
  if (idx >= N_NODES * H_DIM) return;
  int n = idx >> 9;
  int j = idx & 511;
  size_t b = (size_t)n * H3 + j;
  float ir = gi[b], iz = gi[b + 512], inn = gi[b + 1024];
  float hr = gh[b], hz = gh[b + 512], hn = gh[b + 1024];
  float r = 1.0f / (1.0f + expf(-(ir + hr)));
  float z = 1.0f / (1.0f + expf(-(iz + hz)));
  float nv = tanhf(inn + r * hn);
  float hv = (1.0f - z) * nv + z * h[idx];
  u16 hb = f2bf(hv);
  Shi[idx] = hb;
  Slo[idx] = f2bf(hv - bf2f(hb));
}

// ---------------- GCN aggregation + relu + split (+ optional fp32 h) -------
template <bool WF32>
__global__ __launch_bounds__(256) void agg_kernel(
    const float* __restrict__ hW, const int* __restrict__ csr_row,
    const float* __restrict__ csr_norm, const int* __restrict__ offsets,
    const float* __restrict__ selfw, const float* __restrict__ bias,
    u16* __restrict__ Shi, u16* __restrict__ Slo, float* __restrict__ hf32) {
  int gw = (blockIdx.x * blockDim.x + threadIdx.x) >> 6;
  int lane = threadIdx.x & 63;
  int n = gw >> 3;
  int c = ((gw & 7) << 6) | lane;
  if (n >= N_NODES) return;
  int beg = offsets[n], end = offsets[n + 1];
  float acc = 0.0f;
  for (int j = beg; j < end; ++j) {
    int r = csr_row[j];
    float wv = csr_norm[j];
    acc = fmaf(wv, hW[(size_t)r * H_DIM + c], acc);
  }
  float v = acc + selfw[n] * hW[(size_t)n * H_DIM + c] + bias[c];
  v = v > 0.0f ? v : 0.0f;
  size_t o = (size_t)n * H_DIM + c;
  u16 hb = f2bf(v);
  Shi[o] = hb;
  Slo[o] = f2bf(v - bf2f(hb));
  if (WF32) hf32[o] = v;
}

// ---------------- final linear ----------------
__global__ __launch_bounds__(256) void lin_kernel(const float* __restrict__ h,
                                                  const float* __restrict__ lw,
                                                  const float* __restrict__ lb,
                                                  float* __restrict__ out) {
  int gw = (blockIdx.x * blockDim.x + threadIdx.x) >> 6;
  int lane = threadIdx.x & 63;
  if (gw >= N_NODES) return;
  const float* hr = h + (size_t)gw * H_DIM;
  float s = 0.0f;
#pragma unroll
  for (int k = 0; k < H_DIM / 64; ++k) s = fmaf(hr[lane + 64 * k], lw[lane + 64 * k], s);
#pragma unroll
  for (int off = 32; off > 0; off >>= 1) s += __shfl_down(s, off, 64);
  if (lane == 0) out[gw] = s + lb[0];
}

// ---------------- launch ----------------
extern "C" void kernel_launch(void* const* d_in, const int* in_sizes, int n_in,
                              void* d_out, int out_size, void* d_ws, size_t ws_size,
                              hipStream_t stream) {
  const float* xs = (const float*)d_in[0];
  const int* ei = (const int*)d_in[1];
  const float* ew = (const float*)d_in[2];
  const float* W_ih = (const float*)d_in[3];
  const float* W_hh = (const float*)d_in[4];
  const float* b_ih = (const float*)d_in[5];
  const float* b_hh = (const float*)d_in[6];
  const float* conv_W = (const float*)d_in[7];
  const float* conv_b = (const float*)d_in[8];
  const float* lin_W = (const float*)d_in[9];
  const float* lin_b = (const float*)d_in[10];
  float* out = (float*)d_out;

  const int* row = ei;
  const int* col = ei + E_EDGES;

  char* ws = (char*)d_ws;
  size_t off = 0;
  auto alloc = [&](size_t bytes) -> void* {
    void* p = ws + off;
    off += (bytes + 255) & ~(size_t)255;
    return p;
  };
  float* hf32 = (float*)alloc((size_t)MP * H_DIM * 4);
  u16* Shi = (u16*)alloc((size_t)MP * H_DIM * 2);
  u16* Slo = (u16*)alloc((size_t)MP * H_DIM * 2);
  float* gi = (float*)alloc((size_t)MP * H3 * 4);
  float* gh = (float*)alloc((size_t)MP * H3 * 4);
  float* hW = (float*)alloc((size_t)MP * H_DIM * 4);
  u16* xs_hi = (u16*)alloc((size_t)T_STEPS * MP * D_IN * 2);
  u16* xs_lo = (u16*)alloc((size_t)T_STEPS * MP * D_IN * 2);
  u16* Wih_hi = (u16*)alloc((size_t)H3 * D_IN * 2);
  u16* Wih_lo = (u16*)alloc((size_t)H3 * D_IN * 2);
  u16* Whh_hi = (u16*)alloc((size_t)H3 * H_DIM * 2);
  u16* Whh_lo = (u16*)alloc((size_t)H3 * H_DIM * 2);
  u16* Wc_hi = (u16*)alloc((size_t)NUM_CONVS * H_DIM * H_DIM * 2);
  u16* Wc_lo = (u16*)alloc((size_t)NUM_CONVS * H_DIM * H_DIM * 2);
  float* dinv = (float*)alloc(N_NODES * 4);
  float* selfw = (float*)alloc(N_NODES * 4);
  float* csr_norm = (float*)alloc(E_EDGES * 4);
  int* csr_row = (int*)alloc(E_EDGES * 4);
  int* offsets = (int*)alloc((N_NODES + 1) * 4);
  int* counts = (int*)alloc(N_NODES * 4);
  int* cursor = (int*)alloc(N_NODES * 4);

  hipMemsetAsync(hf32, 0, (size_t)MP * H_DIM * 4, stream);
  hipMemsetAsync(Shi, 0, (size_t)MP * H_DIM * 2, stream);
  hipMemsetAsync(Slo, 0, (size_t)MP * H_DIM * 2, stream);
  hipMemsetAsync(dinv, 0, N_NODES * 4, stream);
  hipMemsetAsync(counts, 0, N_NODES * 4, stream);
  hipMemsetAsync(cursor, 0, N_NODES * 4, stream);

  // one-time preprocessing
  deg_kernel<<<(E_EDGES + 255) / 256, 256, 0, stream>>>(col, ew, dinv, counts);
  dinv_kernel<<<(N_NODES + 255) / 256, 256, 0, stream>>>(dinv, selfw);
  scan_kernel<<<1, 1024, 0, stream>>>(counts, offsets, N_NODES);
  scatter_kernel<<<(E_EDGES + 255) / 256, 256, 0, stream>>>(row, col, ew, dinv, offsets,
                                                            cursor, csr_row, csr_norm);
  split_pair<<<(H3 * D_IN + 255) / 256, 256, 0, stream>>>(W_ih, Wih_hi, Wih_lo, H3 * D_IN);
  split_pair<<<(H3 * H_DIM + 255) / 256, 256, 0, stream>>>(W_hh, Whh_hi, Whh_lo, H3 * H_DIM);
  split_convw<<<(NUM_CONVS * H_DIM * H_DIM + 255) / 256, 256, 0, stream>>>(conv_W, Wc_hi, Wc_lo);
  split_xs<<<(T_STEPS * N_NODES * D_IN + 255) / 256, 256, 0, stream>>>(xs, xs_hi, xs_lo);

  dim3 blk(256);
  dim3 g_gru(H3 / 128, MP / 128);
  dim3 g_conv(H_DIM / 128, MP / 128);

  for (int t = 0; t < T_STEPS; ++t) {
    // gh = h_prev @ W_hh^T + b_hh  (reads S split of h_prev)
    gemm_bf16x3<true><<<g_gru, blk, 0, stream>>>(Shi, Slo, Whh_hi, Whh_lo, b_hh, gh,
                                                 N_NODES, H3, H_DIM);
    // gi = x_t @ W_ih^T + b_ih
    gemm_bf16x3<true><<<g_gru, blk, 0, stream>>>(
        xs_hi + (size_t)t * MP * D_IN, xs_lo + (size_t)t * MP * D_IN, Wih_hi, Wih_lo,
        b_ih, gi, N_NODES, H3, D_IN);
    gru_gate_split<<<(N_NODES * H_DIM + 255) / 256, 256, 0, stream>>>(gi, gh, hf32, Shi, Slo);
    for (int l = 0; l < NUM_CONVS; ++l) {
      gemm_bf16x3<false><<<g_conv, blk, 0, stream>>>(
          Shi, Slo, Wc_hi + (size_t)l * H_DIM * H_DIM, Wc_lo + (size_t)l * H_DIM * H_DIM,
          nullptr, hW, N_NODES, H_DIM, H_DIM);
      if (l == NUM_CONVS - 1)
        agg_kernel<true><<<(N_NODES * 8 + 3) / 4, 256, 0, stream>>>(
            hW, csr_row, csr_norm, offsets, selfw, conv_b + l * H_DIM, Shi, Slo, hf32);
      else
        agg_kernel<false><<<(N_NODES * 8 + 3) / 4, 256, 0, stream>>>(
            hW, csr_row, csr_norm, offsets, selfw, conv_b + l * H_DIM, Shi, Slo, hf32);
    }
    lin_kernel<<<(N_NODES + 3) / 4, 256, 0, stream>>>(hf32, lin_W, lin_b,
                                                      out + (size_t)t * N_NODES);
  }
}

// Round 3
// 3891.577 us; speedup vs baseline: 2.2933x; 1.3632x over previous
//
#include <hip/hip_runtime.h>
#include <math.h>

#define T_STEPS 12
#define N_NODES 10000
#define MP 10112  // 79*128, padded M
#define D_IN 256
#define H_DIM 512
#define H3 1536
#define E_EDGES 160000
#define NUM_CONVS 2

typedef __bf16 bf16x8 __attribute__((ext_vector_type(8)));
typedef float floatx4 __attribute__((ext_vector_type(4)));
typedef unsigned short u16;
typedef unsigned int u32;

__device__ __forceinline__ u16 f2bf(float f) {
  unsigned int u = __float_as_uint(f);
  u += 0x7FFFu + ((u >> 16) & 1u);  // round-nearest-even (no NaN inputs)
  return (u16)(u >> 16);
}
__device__ __forceinline__ float bf2f(u16 s) {
  return __uint_as_float(((unsigned int)s) << 16);
}

__device__ __forceinline__ void glds16(const void* g, void* l) {
  __builtin_amdgcn_global_load_lds(
      (const __attribute__((address_space(1))) unsigned int*)g,
      (__attribute__((address_space(3))) unsigned int*)l, 16, 0, 0);
}

// ---------------- bf16x3 MFMA GEMM: C = (Ahi+Alo) @ (Bhi+Blo)^T (+bias) ----
// A*: (rows x K) bf16, rows padded to 128-mult; B*: (Nn x K) bf16.
// Tile 128x128, BK=32, 4 waves of 64x64 (4x4 of 16x16x32 MFMA).
// LDS 16B-slot XOR swizzle: slot(r,c) = r*4 + (c ^ ((r>>1)&3)) -> bank-group-
// uniform frag reads AND contiguous lane order for global_load_lds.
template <bool BIAS>
__global__ __launch_bounds__(256) void gemm_bf16x3(
    const u16* __restrict__ Ahi, const u16* __restrict__ Alo,
    const u16* __restrict__ Bhi, const u16* __restrict__ Blo,
    const float* __restrict__ bias, float* __restrict__ C,
    int M, int Nn, int K) {
  __shared__ u16 lds[4][4096];  // Ahi, Alo, Bhi, Blo tiles (8KB each)
  const int tid = threadIdx.x;
  const int lane = tid & 63;
  const int wave = tid >> 6;
  const int rbase = blockIdx.y * 128;
  const int cbase = blockIdx.x * 128;

  // staging: 512 slots/tile, 2 per thread
  const int s1 = tid, s2 = tid + 256;
  const int r1 = s1 >> 2, c1 = (s1 & 3) ^ ((r1 >> 1) & 3);
  const int r2 = s2 >> 2, c2 = (s2 & 3) ^ ((r2 >> 1) & 3);
  const u16* pah1 = Ahi + (size_t)(rbase + r1) * K + c1 * 8;
  const u16* pah2 = Ahi + (size_t)(rbase + r2) * K + c2 * 8;
  const u16* pal1 = Alo + (size_t)(rbase + r1) * K + c1 * 8;
  const u16* pal2 = Alo + (size_t)(rbase + r2) * K + c2 * 8;
  const u16* pbh1 = Bhi + (size_t)(cbase + r1) * K + c1 * 8;
  const u16* pbh2 = Bhi + (size_t)(cbase + r2) * K + c2 * 8;
  const u16* pbl1 = Blo + (size_t)(cbase + r1) * K + c1 * 8;
  const u16* pbl2 = Blo + (size_t)(cbase + r2) * K + c2 * 8;
  const int l1 = (s1 >> 6) << 9;  // wave-uniform LDS short-offset
  const int l2 = (s2 >> 6) << 9;

  // fragment addressing
  const int wr = (wave >> 1) * 64;
  const int wc = (wave & 1) * 64;
  const int lrow = lane & 15;
  const int kq = lane >> 4;
  const int swz = kq ^ ((lrow >> 1) & 3);
  const int aoff = (wr + lrow) * 32 + swz * 8;
  const int boff = (wc + lrow) * 32 + swz * 8;

  floatx4 acc[4][4];
#pragma unroll
  for (int i = 0; i < 4; ++i)
#pragma unroll
    for (int j = 0; j < 4; ++j) acc[i][j] = (floatx4){0.f, 0.f, 0.f, 0.f};

  for (int kt = 0; kt < K; kt += 32) {
    glds16(pah1 + kt, &lds[0][l1]);
    glds16(pah2 + kt, &lds[0][l2]);
    glds16(pal1 + kt, &lds[1][l1]);
    glds16(pal2 + kt, &lds[1][l2]);
    glds16(pbh1 + kt, &lds[2][l1]);
    glds16(pbh2 + kt, &lds[2][l2]);
    glds16(pbl1 + kt, &lds[3][l1]);
    glds16(pbl2 + kt, &lds[3][l2]);
    __syncthreads();
    bf16x8 ah[4], bh[4], bl[4];
#pragma unroll
    for (int i = 0; i < 4; ++i) ah[i] = *(const bf16x8*)&lds[0][aoff + i * 512];
#pragma unroll
    for (int j = 0; j < 4; ++j) bh[j] = *(const bf16x8*)&lds[2][boff + j * 512];
#pragma unroll
    for (int i = 0; i < 4; ++i)
#pragma unroll
      for (int j = 0; j < 4; ++j)
        acc[i][j] = __builtin_amdgcn_mfma_f32_16x16x32_bf16(ah[i], bh[j], acc[i][j], 0, 0, 0);
#pragma unroll
    for (int j = 0; j < 4; ++j) bl[j] = *(const bf16x8*)&lds[3][boff + j * 512];
#pragma unroll
    for (int i = 0; i < 4; ++i)
#pragma unroll
      for (int j = 0; j < 4; ++j)
        acc[i][j] = __builtin_amdgcn_mfma_f32_16x16x32_bf16(ah[i], bl[j], acc[i][j], 0, 0, 0);
#pragma unroll
    for (int i = 0; i < 4; ++i) {
      bf16x8 al = *(const bf16x8*)&lds[1][aoff + i * 512];
#pragma unroll
      for (int j = 0; j < 4; ++j)
        acc[i][j] = __builtin_amdgcn_mfma_f32_16x16x32_bf16(al, bh[j], acc[i][j], 0, 0, 0);
    }
    __syncthreads();
  }
  // epilogue: C/D layout col=lane&15, row=(lane>>4)*4+reg
#pragma unroll
  for (int j = 0; j < 4; ++j) {
    int col = cbase + wc + j * 16 + lrow;
    float bv = BIAS ? bias[col] : 0.0f;
#pragma unroll
    for (int i = 0; i < 4; ++i) {
      int r0 = rbase + wr + i * 16 + kq * 4;
#pragma unroll
      for (int rr = 0; rr < 4; ++rr) {
        int r = r0 + rr;
        if (r < M) C[(size_t)r * Nn + col] = acc[i][j][rr] + bv;
      }
    }
  }
}

// ---------------- split kernels ----------------
__global__ void split_pair(const float* __restrict__ W, u16* __restrict__ hi,
                           u16* __restrict__ lo, int n) {
  int i = blockIdx.x * 256 + threadIdx.x;
  if (i >= n) return;
  float v = W[i];
  u16 h = f2bf(v);
  hi[i] = h;
  lo[i] = f2bf(v - bf2f(h));
}

// conv_W[l][k][j] -> transposed split [l][j][k]
__global__ void split_convw(const float* __restrict__ W, u16* __restrict__ hi,
                            u16* __restrict__ lo) {
  int o = blockIdx.x * 256 + threadIdx.x;
  if (o >= NUM_CONVS * H_DIM * H_DIM) return;
  int k = o & 511, j = (o >> 9) & 511, l = o >> 18;
  float v = W[(size_t)l * H_DIM * H_DIM + (size_t)k * H_DIM + j];
  u16 h = f2bf(v);
  hi[o] = h;
  lo[o] = f2bf(v - bf2f(h));
}

// xs (T,N,D) -> padded (T,MP,D) bf16 hi/lo
__global__ void split_xs(const float* __restrict__ xs, u16* __restrict__ hi,
                         u16* __restrict__ lo) {
  int i = blockIdx.x * 256 + threadIdx.x;
  if (i >= T_STEPS * N_NODES * D_IN) return;
  int t = i / (N_NODES * D_IN);
  int rem = i - t * (N_NODES * D_IN);
  size_t o = (size_t)t * MP * D_IN + rem;
  float v = xs[i];
  u16 h = f2bf(v);
  hi[o] = h;
  lo[o] = f2bf(v - bf2f(h));
}

// ---------------- graph preprocessing ----------------
__global__ void deg_kernel(const int* __restrict__ col, const float* __restrict__ w,
                           float* __restrict__ deg, int* __restrict__ counts) {
  int e = blockIdx.x * blockDim.x + threadIdx.x;
  if (e >= E_EDGES) return;
  int c = col[e];
  atomicAdd(&deg[c], w[e]);
  atomicAdd(&counts[c], 1);
}

__global__ void dinv_kernel(float* __restrict__ deg_dinv, float* __restrict__ selfw) {
  int n = blockIdx.x * blockDim.x + threadIdx.x;
  if (n >= N_NODES) return;
  float d = deg_dinv[n] + 1.0f;
  float di = 1.0f / sqrtf(d);
  deg_dinv[n] = di;
  selfw[n] = 1.0f / d;
}

__global__ __launch_bounds__(1024) void scan_kernel(const int* __restrict__ counts,
                                                    int* __restrict__ offsets, int n) {
  __shared__ int smem[1024];
  __shared__ int carry_s;
  if (threadIdx.x == 0) carry_s = 0;
  __syncthreads();
  for (int base = 0; base < n; base += 1024) {
    int i = base + threadIdx.x;
    int v = (i < n) ? counts[i] : 0;
    smem[threadIdx.x] = v;
    __syncthreads();
    for (int off = 1; off < 1024; off <<= 1) {
      int t = (threadIdx.x >= off) ? smem[threadIdx.x - off] : 0;
      __syncthreads();
      smem[threadIdx.x] += t;
      __syncthreads();
    }
    if (i < n) offsets[i] = carry_s + smem[threadIdx.x] - v;
    int total = smem[1023];
    __syncthreads();
    if (threadIdx.x == 0) carry_s += total;
    __syncthreads();
  }
  if (threadIdx.x == 0) offsets[n] = carry_s;
}

__global__ void scatter_kernel(const int* __restrict__ row, const int* __restrict__ col,
                               const float* __restrict__ w, const float* __restrict__ dinv,
                               const int* __restrict__ offsets, int* __restrict__ cursor,
                               int* __restrict__ csr_row, float* __restrict__ csr_norm) {
  int e = blockIdx.x * blockDim.x + threadIdx.x;
  if (e >= E_EDGES) return;
  int r = row[e], c = col[e];
  float nrm = dinv[r] * w[e] * dinv[c];
  int pos = offsets[c] + atomicAdd(&cursor[c], 1);
  csr_row[pos] = r;
  csr_norm[pos] = nrm;
}

// ---------------- GRU gates + bf16 split of new h (float4-vectorized) ------
__global__ __launch_bounds__(256) void gru_gate_split(
    const float* __restrict__ gi, const float* __restrict__ gh,
    const float* __restrict__ h, u16* __restrict__ Shi, u16* __restrict__ Slo) {
  int q = blockIdx.x * 256 + threadIdx.x;  // quad index over N*H/4
  if (q >= N_NODES * H_DIM / 4) return;
  int n = q >> 7;
  int j = (q & 127) << 2;
  size_t b = (size_t)n * H3 + j;
  float4 ir = *(const float4*)&gi[b];
  float4 iz = *(const float4*)&gi[b + 512];
  float4 inn = *(const float4*)&gi[b + 1024];
  float4 hr = *(const float4*)&gh[b];
  float4 hz = *(const float4*)&gh[b + 512];
  float4 hn = *(const float4*)&gh[b + 1024];
  size_t o = (size_t)n * H_DIM + j;
  float4 hp = *(const float4*)&h[o];
  float hv[4];
  float irr[4] = {ir.x, ir.y, ir.z, ir.w}, izz[4] = {iz.x, iz.y, iz.z, iz.w},
        inn4[4] = {inn.x, inn.y, inn.z, inn.w}, hrr[4] = {hr.x, hr.y, hr.z, hr.w},
        hzz[4] = {hz.x, hz.y, hz.z, hz.w}, hnn[4] = {hn.x, hn.y, hn.z, hn.w},
        hpp[4] = {hp.x, hp.y, hp.z, hp.w};
#pragma unroll
  for (int k = 0; k < 4; ++k) {
    float r = 1.0f / (1.0f + expf(-(irr[k] + hrr[k])));
    float z = 1.0f / (1.0f + expf(-(izz[k] + hzz[k])));
    float nv = tanhf(inn4[k] + r * hnn[k]);
    hv[k] = (1.0f - z) * nv + z * hpp[k];
  }
  u16 hb[4], lb[4];
#pragma unroll
  for (int k = 0; k < 4; ++k) {
    hb[k] = f2bf(hv[k]);
    lb[k] = f2bf(hv[k] - bf2f(hb[k]));
  }
  u32* ShiP = (u32*)(Shi + o);
  u32* SloP = (u32*)(Slo + o);
  ShiP[0] = (u32)hb[0] | ((u32)hb[1] << 16);
  ShiP[1] = (u32)hb[2] | ((u32)hb[3] << 16);
  SloP[0] = (u32)lb[0] | ((u32)lb[1] << 16);
  SloP[1] = (u32)lb[2] | ((u32)lb[3] << 16);
}

// ---------------- GCN aggregation + relu + split (+ optional fp32 h) -------
// one block per node; wave w handles channels [w*128, w*128+128), float2/lane.
// edge loop unrolled x4 with independent accumulators for memory-level par.
template <bool WF32>
__global__ __launch_bounds__(256) void agg_kernel(
    const float* __restrict__ hW, const int* __restrict__ csr_row,
    const float* __restrict__ csr_norm, const int* __restrict__ offsets,
    const float* __restrict__ selfw, const float* __restrict__ bias,
    u16* __restrict__ Shi, u16* __restrict__ Slo, float* __restrict__ hf32) {
  const int n = blockIdx.x;
  const int lane = threadIdx.x & 63;
  const int wave = threadIdx.x >> 6;
  const int c = (wave << 7) + lane * 2;
  const int beg = offsets[n], end = offsets[n + 1];
  float a0x = 0.f, a0y = 0.f, a1x = 0.f, a1y = 0.f;
  float a2x = 0.f, a2y = 0.f, a3x = 0.f, a3y = 0.f;
  int j = beg;
  for (; j + 4 <= end; j += 4) {
    int r0 = csr_row[j], r1 = csr_row[j + 1], r2 = csr_row[j + 2], r3 = csr_row[j + 3];
    float w0 = csr_norm[j], w1 = csr_norm[j + 1], w2 = csr_norm[j + 2], w3 = csr_norm[j + 3];
    float2 v0 = *(const float2*)&hW[(size_t)r0 * H_DIM + c];
    float2 v1 = *(const float2*)&hW[(size_t)r1 * H_DIM + c];
    float2 v2 = *(const float2*)&hW[(size_t)r2 * H_DIM + c];
    float2 v3 = *(const float2*)&hW[(size_t)r3 * H_DIM + c];
    a0x = fmaf(w0, v0.x, a0x);
    a0y = fmaf(w0, v0.y, a0y);
    a1x = fmaf(w1, v1.x, a1x);
    a1y = fmaf(w1, v1.y, a1y);
    a2x = fmaf(w2, v2.x, a2x);
    a2y = fmaf(w2, v2.y, a2y);
    a3x = fmaf(w3, v3.x, a3x);
    a3y = fmaf(w3, v3.y, a3y);
  }
  for (; j < end; ++j) {
    int r = csr_row[j];
    float w = csr_norm[j];
    float2 v = *(const float2*)&hW[(size_t)r * H_DIM + c];
    a0x = fmaf(w, v.x, a0x);
    a0y = fmaf(w, v.y, a0y);
  }
  float sx = (a0x + a1x) + (a2x + a3x);
  float sy = (a0y + a1y) + (a2y + a3y);
  float sw = selfw[n];
  float2 vs = *(const float2*)&hW[(size_t)n * H_DIM + c];
  float bx = bias[c], by = bias[c + 1];
  float vx = fmaxf(fmaf(sw, vs.x, sx) + bx, 0.0f);
  float vy = fmaxf(fmaf(sw, vs.y, sy) + by, 0.0f);
  size_t o = (size_t)n * H_DIM + c;
  u16 hx = f2bf(vx), hy = f2bf(vy);
  *(u32*)(Shi + o) = (u32)hx | ((u32)hy << 16);
  u16 lx = f2bf(vx - bf2f(hx)), ly = f2bf(vy - bf2f(hy));
  *(u32*)(Slo + o) = (u32)lx | ((u32)ly << 16);
  if (WF32) *(float2*)&hf32[o] = make_float2(vx, vy);
}

// ---------------- final linear ----------------
__global__ __launch_bounds__(256) void lin_kernel(const float* __restrict__ h,
                                                  const float* __restrict__ lw,
                                                  const float* __restrict__ lb,
                                                  float* __restrict__ out) {
  int gw = (blockIdx.x * blockDim.x + threadIdx.x) >> 6;
  int lane = threadIdx.x & 63;
  if (gw >= N_NODES) return;
  const float* hr = h + (size_t)gw * H_DIM;
  float s = 0.0f;
#pragma unroll
  for (int k = 0; k < H_DIM / 64; ++k) s = fmaf(hr[lane + 64 * k], lw[lane + 64 * k], s);
#pragma unroll
  for (int off = 32; off > 0; off >>= 1) s += __shfl_down(s, off, 64);
  if (lane == 0) out[gw] = s + lb[0];
}

// ---------------- launch ----------------
extern "C" void kernel_launch(void* const* d_in, const int* in_sizes, int n_in,
                              void* d_out, int out_size, void* d_ws, size_t ws_size,
                              hipStream_t stream) {
  const float* xs = (const float*)d_in[0];
  const int* ei = (const int*)d_in[1];
  const float* ew = (const float*)d_in[2];
  const float* W_ih = (const float*)d_in[3];
  const float* W_hh = (const float*)d_in[4];
  const float* b_ih = (const float*)d_in[5];
  const float* b_hh = (const float*)d_in[6];
  const float* conv_W = (const float*)d_in[7];
  const float* conv_b = (const float*)d_in[8];
  const float* lin_W = (const float*)d_in[9];
  const float* lin_b = (const float*)d_in[10];
  float* out = (float*)d_out;

  const int* row = ei;
  const int* col = ei + E_EDGES;

  char* ws = (char*)d_ws;
  size_t off = 0;
  auto alloc = [&](size_t bytes) -> void* {
    void* p = ws + off;
    off += (bytes + 255) & ~(size_t)255;
    return p;
  };
  float* hf32 = (float*)alloc((size_t)MP * H_DIM * 4);
  u16* Shi = (u16*)alloc((size_t)MP * H_DIM * 2);
  u16* Slo = (u16*)alloc((size_t)MP * H_DIM * 2);
  float* gi = (float*)alloc((size_t)MP * H3 * 4);
  float* gh = (float*)alloc((size_t)MP * H3 * 4);
  float* hW = (float*)alloc((size_t)MP * H_DIM * 4);
  u16* xs_hi = (u16*)alloc((size_t)T_STEPS * MP * D_IN * 2);
  u16* xs_lo = (u16*)alloc((size_t)T_STEPS * MP * D_IN * 2);
  u16* Wih_hi = (u16*)alloc((size_t)H3 * D_IN * 2);
  u16* Wih_lo = (u16*)alloc((size_t)H3 * D_IN * 2);
  u16* Whh_hi = (u16*)alloc((size_t)H3 * H_DIM * 2);
  u16* Whh_lo = (u16*)alloc((size_t)H3 * H_DIM * 2);
  u16* Wc_hi = (u16*)alloc((size_t)NUM_CONVS * H_DIM * H_DIM * 2);
  u16* Wc_lo = (u16*)alloc((size_t)NUM_CONVS * H_DIM * H_DIM * 2);
  float* dinv = (float*)alloc(N_NODES * 4);
  float* selfw = (float*)alloc(N_NODES * 4);
  float* csr_norm = (float*)alloc(E_EDGES * 4);
  int* csr_row = (int*)alloc(E_EDGES * 4);
  int* offsets = (int*)alloc((N_NODES + 1) * 4);
  int* counts = (int*)alloc(N_NODES * 4);
  int* cursor = (int*)alloc(N_NODES * 4);

  hipMemsetAsync(hf32, 0, (size_t)MP * H_DIM * 4, stream);
  hipMemsetAsync(Shi, 0, (size_t)MP * H_DIM * 2, stream);
  hipMemsetAsync(Slo, 0, (size_t)MP * H_DIM * 2, stream);
  hipMemsetAsync(dinv, 0, N_NODES * 4, stream);
  hipMemsetAsync(counts, 0, N_NODES * 4, stream);
  hipMemsetAsync(cursor, 0, N_NODES * 4, stream);

  // one-time preprocessing
  deg_kernel<<<(E_EDGES + 255) / 256, 256, 0, stream>>>(col, ew, dinv, counts);
  dinv_kernel<<<(N_NODES + 255) / 256, 256, 0, stream>>>(dinv, selfw);
  scan_kernel<<<1, 1024, 0, stream>>>(counts, offsets, N_NODES);
  scatter_kernel<<<(E_EDGES + 255) / 256, 256, 0, stream>>>(row, col, ew, dinv, offsets,
                                                            cursor, csr_row, csr_norm);
  split_pair<<<(H3 * D_IN + 255) / 256, 256, 0, stream>>>(W_ih, Wih_hi, Wih_lo, H3 * D_IN);
  split_pair<<<(H3 * H_DIM + 255) / 256, 256, 0, stream>>>(W_hh, Whh_hi, Whh_lo, H3 * H_DIM);
  split_convw<<<(NUM_CONVS * H_DIM * H_DIM + 255) / 256, 256, 0, stream>>>(conv_W, Wc_hi, Wc_lo);
  split_xs<<<(T_STEPS * N_NODES * D_IN + 255) / 256, 256, 0, stream>>>(xs, xs_hi, xs_lo);

  dim3 blk(256);
  dim3 g_gru(H3 / 128, MP / 128);
  dim3 g_conv(H_DIM / 128, MP / 128);

  for (int t = 0; t < T_STEPS; ++t) {
    // gh = h_prev @ W_hh^T + b_hh  (reads S split of h_prev)
    gemm_bf16x3<true><<<g_gru, blk, 0, stream>>>(Shi, Slo, Whh_hi, Whh_lo, b_hh, gh,
                                                 N_NODES, H3, H_DIM);
    // gi = x_t @ W_ih^T + b_ih
    gemm_bf16x3<true><<<g_gru, blk, 0, stream>>>(
        xs_hi + (size_t)t * MP * D_IN, xs_lo + (size_t)t * MP * D_IN, Wih_hi, Wih_lo,
        b_ih, gi, N_NODES, H3, D_IN);
    gru_gate_split<<<(N_NODES * H_DIM / 4 + 255) / 256, 256, 0, stream>>>(gi, gh, hf32,
                                                                          Shi, Slo);
    for (int l = 0; l < NUM_CONVS; ++l) {
      gemm_bf16x3<false><<<g_conv, blk, 0, stream>>>(
          Shi, Slo, Wc_hi + (size_t)l * H_DIM * H_DIM, Wc_lo + (size_t)l * H_DIM * H_DIM,
          nullptr, hW, N_NODES, H_DIM, H_DIM);
      if (l == NUM_CONVS - 1)
        agg_kernel<true><<<N_NODES, 256, 0, stream>>>(
            hW, csr_row, csr_norm, offsets, selfw, conv_b + l * H_DIM, Shi, Slo, hf32);
      else
        agg_kernel<false><<<N_NODES, 256, 0, stream>>>(
            hW, csr_row, csr_norm, offsets, selfw, conv_b + l * H_DIM, Shi, Slo, hf32);
    }
    lin_kernel<<<(N_NODES + 3) / 4, 256, 0, stream>>>(hf32, lin_W, lin_b,
                                                      out + (size_t)t * N_NODES);
  }
}